// Round 5
// baseline (827.295 us; speedup 1.0000x reference)
//
#include <hip/hip_runtime.h>

#define NN 128
#define NE 4096
#define DD 130
#define HH 64
#define KK1 8320   // D*H
#define CC 256     // ea-value chunks
#define NSEG 16
#define SEGC 16    // chunks per segment
#define KHW 4160   // half row width (65 i's x 64 o's)

// workspace layout (float offsets)
#define OFF_XR1  0            // 8192
#define OFF_H1   8192         // 8192
#define OFF_HB2  16384        // 8192
#define OFF_HR2  24576        // 8192
#define OFF_H2   32768        // 8192
#define OFF_AGG2 40960        // 8192 (fully written)
#define OFF_G2   49152        // 524288 -> 573440
#define OFF_MSG  573440       // 2 * NE*64 = 524288 -> 1097728
#define OFF_SP   1097728      // CC*KK1 = 2129920 -> 3227648
#define OFF_SQ   3227648      // -> 5357568
#define OFF_DP   5357568      // -> 7487488
#define OFF_DQ   7487488      // -> 9617408
#define OFF_TP   9617408      // NSEG*KK1 = 133120 -> 9750528
#define OFF_TQ   9750528      // -> 9883648
#define OFF_INT  9883648      // ints: 25476 slots

// Event bin for threshold t_k = -c/a within [0,1): chunk in which k flips.
__device__ __forceinline__ int event_bin(float a, float c) {
  if (a > 0.f) {
    if (c <= 0.f) { float tt = -c / a; if (tt < 1.f) return (int)(tt * 256.0f); }
  } else if (a < 0.f) {
    if (c > 0.f) { float tt = -c / a; if (tt < 1.f) return (int)ceilf(tt * 256.0f) - 1; }
  }
  return -1;
}

// ---------- counts, chunk lists for edges / k-events / base rows / dst-CSR ----------
__global__ __launch_bounds__(256) void k_count(const int* __restrict__ ei,
                                               const float* __restrict__ eattr,
                                               const float* __restrict__ W1a,
                                               const float* __restrict__ b1a,
                                               int* __restrict__ e_off,
                                               int* __restrict__ k_off,
                                               int* __restrict__ e_idx,
                                               int* __restrict__ k_idx,
                                               int* __restrict__ base_idx,
                                               int* __restrict__ nbase,
                                               int* __restrict__ d_off,
                                               int* __restrict__ perm_dst) {
  __shared__ int ec[CC], kc[CC], cd[NN];
  __shared__ int eo[CC + 1], ko[CC + 1], doff[NN + 1];
  __shared__ int bcnt;
  int t = threadIdx.x;
  ec[t] = 0; kc[t] = 0;
  if (t < NN) cd[t] = 0;
  if (t == 0) bcnt = 0;
  __syncthreads();
  for (int e = t; e < NE; e += 256) {
    atomicAdd(&cd[ei[NE + e]], 1);
    int c = (int)(eattr[e] * 256.0f); c = c < 0 ? 0 : (c > CC - 1 ? CC - 1 : c);
    atomicAdd(&ec[c], 1);
  }
  for (int k = t; k < KK1; k += 256) {
    int b = event_bin(W1a[k], b1a[k]);
    if (b >= 0) atomicAdd(&kc[b], 1);
    if (b1a[k] > 0.f) { int p = atomicAdd(&bcnt, 1); base_idx[p] = k; }
  }
  __syncthreads();
  if (t == 0) {
    *nbase = bcnt;
    int r = 0;
    for (int c = 0; c < CC; c++) { eo[c] = r; r += ec[c]; } eo[CC] = r;
    r = 0;
    for (int c = 0; c < CC; c++) { ko[c] = r; r += kc[c]; } ko[CC] = r;
    r = 0;
    for (int n = 0; n < NN; n++) { doff[n] = r; r += cd[n]; } doff[NN] = r;
  }
  __syncthreads();
  if (t < NN) d_off[t] = doff[t];
  if (t == 0) d_off[NN] = doff[NN];
  e_off[t] = eo[t]; k_off[t] = ko[t];
  if (t == 0) { e_off[CC] = eo[CC]; k_off[CC] = ko[CC]; }
  ec[t] = eo[t]; kc[t] = ko[t];        // cursors
  if (t < NN) cd[t] = doff[t];         // dst cursor
  __syncthreads();
  for (int e = t; e < NE; e += 256) {
    int c = (int)(eattr[e] * 256.0f); c = c < 0 ? 0 : (c > CC - 1 ? CC - 1 : c);
    int p = atomicAdd(&ec[c], 1);
    e_idx[p] = e;
    int d = ei[NE + e];
    int pd = atomicAdd(&cd[d], 1);
    perm_dst[pd] = e;
  }
  for (int k = t; k < KK1; k += 256) {
    int b = event_bin(W1a[k], b1a[k]);
    if (b >= 0) { int p = atomicAdd(&kc[b], 1); k_idx[p] = k; }
  }
}

// ---------- fused: S row-0 init (SP0=0, SQ0=b1b) + xr1 = x@Wr1 ----------
__global__ __launch_bounds__(256) void k_pre(const float* __restrict__ b1b,
                                             const float* __restrict__ x,
                                             const float* __restrict__ Wr1,
                                             float* __restrict__ SP0,
                                             float* __restrict__ SQ0,
                                             float* __restrict__ xr1) {
  int f = blockIdx.x * 256 + threadIdx.x;   // grid 33 -> 8448
  if (f < KK1) { SP0[f] = 0.f; SQ0[f] = b1b[f]; }
  if (f < NN * HH) {
    int n = f >> 6, o = f & 63;
    float a = 0.f;
    for (int i = 0; i < DD; i++) a = fmaf(x[n * DD + i], Wr1[i * HH + o], a);
    xr1[f] = a;
  }
}

// ---------- base state, column-owner axis: 8-way atomics only ----------
__global__ __launch_bounds__(256) void k_base(const float* __restrict__ W1a,
                                              const float* __restrict__ b1a,
                                              const float* __restrict__ W1b,
                                              const int* __restrict__ base_idx,
                                              const int* __restrict__ nbase,
                                              float* __restrict__ SP0,
                                              float* __restrict__ SQ0) {
  int col = blockIdx.x * 256 + threadIdx.x;   // grid (33, 8)
  bool valid = col < KK1;
  int nb = *nbase;
  float rp = 0.f, rq = 0.f;
  for (int r = blockIdx.y; r < nb; r += 8) {
    int k = base_idx[r];
    float a = W1a[k], c2 = b1a[k];
    float w = valid ? W1b[(long)k * KK1 + col] : 0.f;
    rp = fmaf(a, w, rp);
    rq = fmaf(c2, w, rq);
  }
  if (valid) {
    atomicAdd(&SP0[col], rp);
    atomicAdd(&SQ0[col], rq);
  }
}

// ---------- per-chunk diffs: D_c = sum over events in chunk c of (sa*w, sc*w) ----------
#define MCOL 33   // ceil(8320/256)
__global__ __launch_bounds__(256) void k_diff(const float* __restrict__ W1a,
                                              const float* __restrict__ b1a,
                                              const float* __restrict__ W1b,
                                              const int* __restrict__ k_off,
                                              const int* __restrict__ k_idx,
                                              float* __restrict__ DP,
                                              float* __restrict__ DQ) {
  int c = blockIdx.x, t = threadIdx.x;
  int kb = k_off[c], ke = k_off[c + 1];
  float rp[MCOL], rq[MCOL];
#pragma unroll
  for (int m = 0; m < MCOL; m++) { rp[m] = 0.f; rq[m] = 0.f; }
  for (int r = kb; r < ke; ++r) {
    int k = k_idx[r];
    float a = W1a[k], c2 = b1a[k];
    float sa = (a > 0.f) ? a : -a;
    float sc = (a > 0.f) ? c2 : -c2;
    const float* row = &W1b[(long)k * KK1];
#pragma unroll
    for (int m = 0; m < MCOL; m++) {
      int col = t + 256 * m;
      if (col < KK1) {
        float w = row[col];
        rp[m] = fmaf(sa, w, rp[m]);
        rq[m] = fmaf(sc, w, rq[m]);
      }
    }
  }
#pragma unroll
  for (int m = 0; m < MCOL; m++) {
    int col = t + 256 * m;
    if (col < KK1) {
      DP[(long)c * KK1 + col] = rp[m];
      DQ[(long)c * KK1 + col] = rq[m];
    }
  }
}

// ---------- segment sums ----------
__global__ __launch_bounds__(256) void k_seg(const float* __restrict__ DP,
                                             const float* __restrict__ DQ,
                                             float* __restrict__ TP,
                                             float* __restrict__ TQ) {
  int f = blockIdx.x * 256 + threadIdx.x;   // < 16640 exact
  int s = blockIdx.y;
  const float* Dm; float* T; int col;
  if (f < KK1) { Dm = DP; T = TP; col = f; }
  else         { Dm = DQ; T = TQ; col = f - KK1; }
  float a = 0.f;
  for (int p = 0; p < SEGC; p++) a += Dm[(long)(s * SEGC + p) * KK1 + col];
  T[(long)s * KK1 + col] = a;
}

// ---------- scan: S[c] = S[0] + prefix(T) + in-segment prefix(D) ----------
__global__ __launch_bounds__(256) void k_scan(float* __restrict__ SP,
                                              float* __restrict__ SQ,
                                              const float* __restrict__ DP,
                                              const float* __restrict__ DQ,
                                              const float* __restrict__ TP,
                                              const float* __restrict__ TQ) {
  int f = blockIdx.x * 256 + threadIdx.x;   // < 16640
  int s = blockIdx.y;
  float* S; const float* Dm; const float* T; int col;
  if (f < KK1) { S = SP; Dm = DP; T = TP; col = f; }
  else         { S = SQ; Dm = DQ; T = TQ; col = f - KK1; }
  float acc = S[col];                       // row 0 (never rewritten)
  for (int sp = 0; sp < s; sp++) acc += T[(long)sp * KK1 + col];
  for (int p = 0; p < SEGC; p++) {
    int c = s * SEGC + p;
    if (c > 0) S[(long)c * KK1 + col] = acc;
    acc += Dm[(long)c * KK1 + col];
  }
}

// ---------- per-chunk sweep, i-split (contiguous halves); msg write, no atomics ----------
#define EC 192
#define KC 128
__global__ __launch_bounds__(256) void k_sweep(const float* __restrict__ SP,
                                               const float* __restrict__ SQ,
                                               const float* __restrict__ W1a,
                                               const float* __restrict__ b1a,
                                               const float* __restrict__ W1b,
                                               const float* __restrict__ x,
                                               const float* __restrict__ eattr,
                                               const int* __restrict__ ei,
                                               const int* __restrict__ e_off,
                                               const int* __restrict__ e_idx,
                                               const int* __restrict__ k_off,
                                               const int* __restrict__ k_idx,
                                               float* __restrict__ msg) {
  __shared__ float Pl[KHW], Ql[KHW];
  __shared__ float eas[EC], eas_r[EC];
  __shared__ int eix[EC], eix_r[EC];
  __shared__ float tks[KC], tks_r[KC];
  __shared__ int kix[KC], kix_r[KC];
  int c = blockIdx.x, ih = blockIdx.y, t = threadIdx.x;
  int jb = ih * KHW;                        // contiguous column base
  int eb = e_off[c], ne = e_off[c + 1] - eb; if (ne > EC) ne = EC;
  int kb = k_off[c], nk = k_off[c + 1] - kb; if (nk > KC) nk = KC;
  for (int j = t; j < KHW; j += 256) {
    Pl[j] = SP[(long)c * KK1 + jb + j];
    Ql[j] = SQ[(long)c * KK1 + jb + j];
  }
  if (t < ne) { int e = e_idx[eb + t]; eix_r[t] = e; eas_r[t] = eattr[e]; }
  if (t < nk) {
    int k = k_idx[kb + t];
    kix_r[t] = k;
    tks_r[t] = -b1a[k] / W1a[k];
  }
  __syncthreads();
  if (t < ne) {  // rank sort edges by ea
    float key = eas_r[t]; int rk = 0;
    for (int j = 0; j < ne; j++) { float kj = eas_r[j]; rk += (kj < key) || (kj == key && j < t); }
    eas[rk] = key; eix[rk] = eix_r[t];
  }
  if (t < nk) {  // rank sort events by threshold
    float key = tks_r[t]; int rk = 0;
    for (int j = 0; j < nk; j++) { float kj = tks_r[j]; rk += (kj < key) || (kj == key && j < t); }
    tks[rk] = key; kix[rk] = kix_r[t];
  }
  __syncthreads();
  if (ne == 0) return;
  int ie = 0, ik = 0;
  int q = t >> 6, o = t & 63;               // 4 edge slots x 64 outputs
  float* mbase = msg + (long)ih * (NE * 64);
  while (ie < ne) {
    int me = 0;
    while (ik + me < nk && tks[ik + me] < eas[ie]) me++;
    if (me > 0) {
      __syncthreads();                      // prior edge reads of Pl/Ql done
      for (int ev = 0; ev < me; ev++) {     // threads own disjoint j's: no inner barrier
        int k = kix[ik + ev];
        float a = W1a[k], c2 = b1a[k];
        float sa = (a > 0.f) ? a : -a;
        float sc = (a > 0.f) ? c2 : -c2;
        const float* row = &W1b[(long)k * KK1 + jb];
        for (int j = t; j < KHW; j += 256) {
          float w = row[j];
          Pl[j] = fmaf(sa, w, Pl[j]);
          Ql[j] = fmaf(sc, w, Ql[j]);
        }
      }
      __syncthreads();
      ik += me;
    }
    int m = 1;
    while (ie + m < ne && (ik >= nk || eas[ie + m] <= tks[ik])) m++;
    for (int g = 0; g < m; g += 4) {
      int sl = g + q;
      if (sl < m) {
        int e = eix[ie + sl];
        float eav = eas[ie + sl];
        int s = ei[e];
        const float* xp = &x[s * DD + ih * 65];
        float A = 0.f, B = 0.f;
#pragma unroll 5
        for (int i = 0; i < 65; i++) {
          float xv = xp[i];
          A = fmaf(xv, Pl[i * 64 + o], A);
          B = fmaf(xv, Ql[i * 64 + o], B);
        }
        mbase[e * 64 + o] = fmaf(eav, A, B);
      }
    }
    ie += m;
  }
}

// ---------- gather msg halves by dst-CSR + mean + root + bias + relu ----------
__global__ __launch_bounds__(256) void k_aggh(const float* __restrict__ msg,
                                              const int* __restrict__ d_off,
                                              const int* __restrict__ perm_dst,
                                              const float* __restrict__ xr1,
                                              const float* __restrict__ bc1,
                                              float* __restrict__ h1) {
  int f = blockIdx.x * 256 + threadIdx.x;   // < 8192
  int n = f >> 6, o = f & 63;
  int b0 = d_off[n], b1 = d_off[n + 1];
  float v = 0.f;
  for (int r = b0; r < b1; r++) {
    int e = perm_dst[r];
    v += msg[e * 64 + o] + msg[NE * 64 + e * 64 + o];
  }
  float cn = fmaxf((float)(b1 - b0), 1.f);
  h1[f] = fmaxf(0.f, v / cn + xr1[f] + bc1[o]);
}

// ---------- fused: G2 = h1-dependent per-src weights, hb2/hr2 small mats ----------
__global__ __launch_bounds__(256) void k_g2s(const float* __restrict__ h1,
                                             const float* __restrict__ W2b,
                                             const float* __restrict__ b2b,
                                             const float* __restrict__ Wr2,
                                             float* __restrict__ G2,
                                             float* __restrict__ hb2,
                                             float* __restrict__ hr2) {
  int bx = blockIdx.x, t = threadIdx.x;
  if (bx < 2048) {
    int f = bx * 256 + t;  // < 128*64*64
    int s = f >> 12, k = (f >> 6) & 63, o = f & 63;
    const float* hp = &h1[s * 64];
    const float* wp = &W2b[k * 4096 + o];
    float a = 0.f;
    for (int i = 0; i < 64; i++) a = fmaf(hp[i], wp[i * 64], a);
    G2[f] = a;
  } else {
    int f = (bx - 2048) * 256 + t;  // < 8192
    int n = f >> 6, o = f & 63;
    float a = 0.f, b = 0.f;
    for (int i = 0; i < 64; i++) {
      float hv = h1[n * 64 + i];
      a = fmaf(hv, b2b[i * 64 + o], a);
      b = fmaf(hv, Wr2[i * 64 + o], b);
    }
    hb2[f] = a; hr2[f] = b;
  }
}

// ---------- conv2: dst-gather (CSR), no atomics; agg2 fully written ----------
__global__ __launch_bounds__(256) void k_consume2(const float* __restrict__ G2,
                                                  const float* __restrict__ W2a,
                                                  const float* __restrict__ b2a,
                                                  const float* __restrict__ eattr,
                                                  const int* __restrict__ ei,
                                                  const int* __restrict__ d_off,
                                                  const int* __restrict__ perm_dst,
                                                  const float* __restrict__ hb2,
                                                  float* __restrict__ agg2) {
  __shared__ float wa[64], wb[64];
  __shared__ float red[8][32];
  int n = blockIdx.x, oh = blockIdx.y, t = threadIdx.x;
  int sl = t >> 5, ol = t & 31;
  if (t < 64) { wa[t] = W2a[t]; wb[t] = b2a[t]; }
  __syncthreads();
  int b0 = d_off[n], b1 = d_off[n + 1];
  float acc = 0.f;
  for (int r = b0 + sl; r < b1; r += 8) {
    int e = perm_dst[r];
    int s = ei[e];
    float ev = eattr[e];
    const float* gp = &G2[s * 4096 + oh * 32 + ol];
    float a = hb2[s * 64 + oh * 32 + ol];
    for (int k = 0; k < 64; k++) {
      float u = fmaxf(0.f, fmaf(ev, wa[k], wb[k]));
      a = fmaf(u, gp[k * 64], a);
    }
    acc += a;
  }
  red[sl][ol] = acc;
  __syncthreads();
  if (sl == 0) {
    float a = 0.f;
#pragma unroll
    for (int j = 0; j < 8; j++) a += red[j][ol];
    agg2[n * 64 + oh * 32 + ol] = a;
  }
}

// ---------- h2 = relu(agg2/cnt + hr2 + bc2), cnt from d_off ----------
__global__ __launch_bounds__(256) void k_h2d(const float* __restrict__ agg,
                                             const int* __restrict__ d_off,
                                             const float* __restrict__ xr,
                                             const float* __restrict__ bc,
                                             float* __restrict__ h) {
  int f = blockIdx.x * 256 + threadIdx.x;  // < 8192
  int n = f >> 6, o = f & 63;
  float c = fmaxf((float)(d_off[n + 1] - d_off[n]), 1.f);
  h[f] = fmaxf(0.f, agg[f] / c + xr[f] + bc[o]);
}

// ---------- logits -> masked softmax -> packet-mask rows ----------
__global__ __launch_bounds__(128) void k_out(const float* __restrict__ h2,
                                             const float* __restrict__ Wout,
                                             const float* __restrict__ bout,
                                             const int* __restrict__ adj,
                                             const float* __restrict__ npk,
                                             float* __restrict__ out) {
  __shared__ float hs[64];
  __shared__ float redm[2], reds[2];
  int n = blockIdx.x, j = threadIdx.x;
  if (j < 64) hs[j] = h2[n * 64 + j];
  __syncthreads();
  float l = bout[j];
  for (int k = 0; k < 64; k++) l = fmaf(hs[k], Wout[k * 128 + j], l);
  bool am = adj[n * 128 + j] != 0;
  float lm = am ? l : -3.0e38f;
  float m = lm;
  for (int off = 32; off >= 1; off >>= 1) m = fmaxf(m, __shfl_xor(m, off, 64));
  int wid = j >> 6;
  if ((j & 63) == 0) redm[wid] = m;
  __syncthreads();
  m = fmaxf(redm[0], redm[1]);
  float p = am ? expf(lm - m) : 0.f;
  float sv = p;
  for (int off = 32; off >= 1; off >>= 1) sv += __shfl_xor(sv, off, 64);
  if ((j & 63) == 0) reds[wid] = sv;
  __syncthreads();
  sv = reds[0] + reds[1];
  float prob = p / sv;
  bool haspkt = (npk[n] != -1.0f);
  out[n * 128 + j] = haspkt ? prob : ((j == n) ? 1.f : 0.f);
}

extern "C" void kernel_launch(void* const* d_in, const int* in_sizes, int n_in,
                              void* d_out, int out_size, void* d_ws, size_t ws_size,
                              hipStream_t stream) {
  const float* x    = (const float*)d_in[0];
  const int*   ei   = (const int*)  d_in[1];
  const float* ea   = (const float*)d_in[2];
  const int*   adj  = (const int*)  d_in[3];
  const float* npk  = (const float*)d_in[4];
  const float* W1a  = (const float*)d_in[5];
  const float* b1a  = (const float*)d_in[6];
  const float* W1b  = (const float*)d_in[7];
  const float* b1b  = (const float*)d_in[8];
  const float* Wr1  = (const float*)d_in[9];
  const float* bc1  = (const float*)d_in[10];
  const float* W2a  = (const float*)d_in[11];
  const float* b2a  = (const float*)d_in[12];
  const float* W2b  = (const float*)d_in[13];
  const float* b2b  = (const float*)d_in[14];
  const float* Wr2  = (const float*)d_in[15];
  const float* bc2  = (const float*)d_in[16];
  const float* Wout = (const float*)d_in[17];
  const float* bout = (const float*)d_in[18];

  float* ws = (float*)d_ws;
  int*   ip = (int*)(ws + OFF_INT);
  int* e_off    = ip;
  int* k_off    = ip + 257;
  int* e_idx    = ip + 514;
  int* k_idx    = ip + 4610;
  int* base_idx = ip + 12930;
  int* nbase    = ip + 21250;
  int* d_off    = ip + 21251;
  int* perm_dst = ip + 21380;

  k_count<<<1, 256, 0, stream>>>(ei, ea, W1a, b1a, e_off, k_off, e_idx, k_idx,
                                 base_idx, nbase, d_off, perm_dst);
  k_pre<<<33, 256, 0, stream>>>(b1b, x, Wr1, ws + OFF_SP, ws + OFF_SQ, ws + OFF_XR1);
  k_base<<<dim3(33, 8), 256, 0, stream>>>(W1a, b1a, W1b, base_idx, nbase,
                                          ws + OFF_SP, ws + OFF_SQ);
  k_diff<<<CC, 256, 0, stream>>>(W1a, b1a, W1b, k_off, k_idx, ws + OFF_DP, ws + OFF_DQ);
  k_seg<<<dim3(65, NSEG), 256, 0, stream>>>(ws + OFF_DP, ws + OFF_DQ,
                                            ws + OFF_TP, ws + OFF_TQ);
  k_scan<<<dim3(65, NSEG), 256, 0, stream>>>(ws + OFF_SP, ws + OFF_SQ,
                                             ws + OFF_DP, ws + OFF_DQ,
                                             ws + OFF_TP, ws + OFF_TQ);
  k_sweep<<<dim3(CC, 2), 256, 0, stream>>>(ws + OFF_SP, ws + OFF_SQ, W1a, b1a, W1b,
                                           x, ea, ei, e_off, e_idx, k_off, k_idx,
                                           ws + OFF_MSG);
  k_aggh<<<32, 256, 0, stream>>>(ws + OFF_MSG, d_off, perm_dst, ws + OFF_XR1, bc1,
                                 ws + OFF_H1);
  k_g2s<<<2080, 256, 0, stream>>>(ws + OFF_H1, W2b, b2b, Wr2,
                                  ws + OFF_G2, ws + OFF_HB2, ws + OFF_HR2);
  k_consume2<<<dim3(NN, 2), 256, 0, stream>>>(ws + OFF_G2, W2a, b2a, ea, ei,
                                              d_off, perm_dst, ws + OFF_HB2,
                                              ws + OFF_AGG2);
  k_h2d<<<32, 256, 0, stream>>>(ws + OFF_AGG2, d_off, ws + OFF_HR2, bc2, ws + OFF_H2);
  k_out<<<128, 128, 0, stream>>>(ws + OFF_H2, Wout, bout, adj, npk, (float*)d_out);
}

// Round 6
// 668.688 us; speedup vs baseline: 1.2372x; 1.2372x over previous
//
#include <hip/hip_runtime.h>

#define NN 128
#define NE 4096
#define DD 130
#define HH 64
#define KK1 8320   // D*H
#define CC 256     // ea-value chunks
#define NSEG 16
#define SEGC 16    // chunks per segment
#define KHW 4160   // half row width (65 i's x 64 o's)

// workspace layout (float offsets)
#define OFF_XR1  0            // 8192
#define OFF_H1   8192         // 8192
#define OFF_HB2  16384        // 8192
#define OFF_HR2  24576        // 8192
#define OFF_H2   32768        // 8192
#define OFF_AGG2 40960        // 8192 (fully written)
#define OFF_G2   49152        // 524288 -> 573440
#define OFF_MSG  573440       // 2 * NE*64 = 524288 -> 1097728
#define OFF_SP   1097728      // CC*KK1 = 2129920 -> 3227648
#define OFF_SQ   3227648      // -> 5357568
#define OFF_DP   5357568      // -> 7487488
#define OFF_DQ   7487488      // -> 9617408
#define OFF_TP   9617408      // NSEG*KK1 = 133120 -> 9750528
#define OFF_TQ   9750528      // -> 9883648
#define OFF_INT  9883648      // ints: 25476 slots

// Event bin for threshold t_k = -c/a within [0,1): chunk in which k flips.
__device__ __forceinline__ int event_bin(float a, float c) {
  if (a > 0.f) {
    if (c <= 0.f) { float tt = -c / a; if (tt < 1.f) return (int)(tt * 256.0f); }
  } else if (a < 0.f) {
    if (c > 0.f) { float tt = -c / a; if (tt < 1.f) return (int)ceilf(tt * 256.0f) - 1; }
  }
  return -1;
}

// ---------- counts, chunk lists for edges / k-events / base rows / dst-CSR ----------
__global__ __launch_bounds__(256) void k_count(const int* __restrict__ ei,
                                               const float* __restrict__ eattr,
                                               const float* __restrict__ W1a,
                                               const float* __restrict__ b1a,
                                               int* __restrict__ e_off,
                                               int* __restrict__ k_off,
                                               int* __restrict__ e_idx,
                                               int* __restrict__ k_idx,
                                               int* __restrict__ base_idx,
                                               int* __restrict__ nbase,
                                               int* __restrict__ d_off,
                                               int* __restrict__ perm_dst) {
  __shared__ int ec[CC], kc[CC], cd[NN];
  __shared__ int eo[CC + 1], ko[CC + 1], doff[NN + 1];
  __shared__ int bcnt;
  int t = threadIdx.x;
  ec[t] = 0; kc[t] = 0;
  if (t < NN) cd[t] = 0;
  if (t == 0) bcnt = 0;
  __syncthreads();
  for (int e = t; e < NE; e += 256) {
    atomicAdd(&cd[ei[NE + e]], 1);
    int c = (int)(eattr[e] * 256.0f); c = c < 0 ? 0 : (c > CC - 1 ? CC - 1 : c);
    atomicAdd(&ec[c], 1);
  }
  for (int k = t; k < KK1; k += 256) {
    int b = event_bin(W1a[k], b1a[k]);
    if (b >= 0) atomicAdd(&kc[b], 1);
    if (b1a[k] > 0.f) { int p = atomicAdd(&bcnt, 1); base_idx[p] = k; }
  }
  __syncthreads();
  if (t == 0) {
    *nbase = bcnt;
    int r = 0;
    for (int c = 0; c < CC; c++) { eo[c] = r; r += ec[c]; } eo[CC] = r;
    r = 0;
    for (int c = 0; c < CC; c++) { ko[c] = r; r += kc[c]; } ko[CC] = r;
    r = 0;
    for (int n = 0; n < NN; n++) { doff[n] = r; r += cd[n]; } doff[NN] = r;
  }
  __syncthreads();
  if (t < NN) d_off[t] = doff[t];
  if (t == 0) d_off[NN] = doff[NN];
  e_off[t] = eo[t]; k_off[t] = ko[t];
  if (t == 0) { e_off[CC] = eo[CC]; k_off[CC] = ko[CC]; }
  ec[t] = eo[t]; kc[t] = ko[t];        // cursors
  if (t < NN) cd[t] = doff[t];         // dst cursor
  __syncthreads();
  for (int e = t; e < NE; e += 256) {
    int c = (int)(eattr[e] * 256.0f); c = c < 0 ? 0 : (c > CC - 1 ? CC - 1 : c);
    int p = atomicAdd(&ec[c], 1);
    e_idx[p] = e;
    int d = ei[NE + e];
    int pd = atomicAdd(&cd[d], 1);
    perm_dst[pd] = e;
  }
  for (int k = t; k < KK1; k += 256) {
    int b = event_bin(W1a[k], b1a[k]);
    if (b >= 0) { int p = atomicAdd(&kc[b], 1); k_idx[p] = k; }
  }
}

// ---------- fused: S row-0 init (SP0=0, SQ0=b1b) + xr1 = x@Wr1 ----------
__global__ __launch_bounds__(256) void k_pre(const float* __restrict__ b1b,
                                             const float* __restrict__ x,
                                             const float* __restrict__ Wr1,
                                             float* __restrict__ SP0,
                                             float* __restrict__ SQ0,
                                             float* __restrict__ xr1) {
  int f = blockIdx.x * 256 + threadIdx.x;   // grid 33 -> 8448
  if (f < KK1) { SP0[f] = 0.f; SQ0[f] = b1b[f]; }
  if (f < NN * HH) {
    int n = f >> 6, o = f & 63;
    float a = 0.f;
    for (int i = 0; i < DD; i++) a = fmaf(x[n * DD + i], Wr1[i * HH + o], a);
    xr1[f] = a;
  }
}

// ---------- base state: row-streaming, register accumulators, 128-way atomics ----------
#define MCOL 33   // ceil(8320/256)
__global__ __launch_bounds__(256) void k_base(const float* __restrict__ W1a,
                                              const float* __restrict__ b1a,
                                              const float* __restrict__ W1b,
                                              const int* __restrict__ base_idx,
                                              const int* __restrict__ nbase,
                                              float* __restrict__ SP0,
                                              float* __restrict__ SQ0) {
  int t = threadIdx.x;
  int nb = *nbase;
  float rp[MCOL], rq[MCOL];
#pragma unroll
  for (int m = 0; m < MCOL; m++) { rp[m] = 0.f; rq[m] = 0.f; }
  for (int r = blockIdx.x; r < nb; r += 128) {
    int k = base_idx[r];
    float a = W1a[k], c2 = b1a[k];
    const float* row = &W1b[(long)k * KK1];
#pragma unroll
    for (int m = 0; m < MCOL; m++) {
      int col = t + 256 * m;
      if (col < KK1) {
        float w = row[col];
        rp[m] = fmaf(a, w, rp[m]);
        rq[m] = fmaf(c2, w, rq[m]);
      }
    }
  }
#pragma unroll
  for (int m = 0; m < MCOL; m++) {
    int col = t + 256 * m;
    if (col < KK1) {
      atomicAdd(&SP0[col], rp[m]);
      atomicAdd(&SQ0[col], rq[m]);
    }
  }
}

// ---------- per-chunk diffs: D_c = sum over events in chunk c of (sa*w, sc*w) ----------
__global__ __launch_bounds__(256) void k_diff(const float* __restrict__ W1a,
                                              const float* __restrict__ b1a,
                                              const float* __restrict__ W1b,
                                              const int* __restrict__ k_off,
                                              const int* __restrict__ k_idx,
                                              float* __restrict__ DP,
                                              float* __restrict__ DQ) {
  int c = blockIdx.x, t = threadIdx.x;
  int kb = k_off[c], ke = k_off[c + 1];
  float rp[MCOL], rq[MCOL];
#pragma unroll
  for (int m = 0; m < MCOL; m++) { rp[m] = 0.f; rq[m] = 0.f; }
  for (int r = kb; r < ke; ++r) {
    int k = k_idx[r];
    float a = W1a[k], c2 = b1a[k];
    float sa = (a > 0.f) ? a : -a;
    float sc = (a > 0.f) ? c2 : -c2;
    const float* row = &W1b[(long)k * KK1];
#pragma unroll
    for (int m = 0; m < MCOL; m++) {
      int col = t + 256 * m;
      if (col < KK1) {
        float w = row[col];
        rp[m] = fmaf(sa, w, rp[m]);
        rq[m] = fmaf(sc, w, rq[m]);
      }
    }
  }
#pragma unroll
  for (int m = 0; m < MCOL; m++) {
    int col = t + 256 * m;
    if (col < KK1) {
      DP[(long)c * KK1 + col] = rp[m];
      DQ[(long)c * KK1 + col] = rq[m];
    }
  }
}

// ---------- segment sums ----------
__global__ __launch_bounds__(256) void k_seg(const float* __restrict__ DP,
                                             const float* __restrict__ DQ,
                                             float* __restrict__ TP,
                                             float* __restrict__ TQ) {
  int f = blockIdx.x * 256 + threadIdx.x;   // < 16640 exact
  int s = blockIdx.y;
  const float* Dm; float* T; int col;
  if (f < KK1) { Dm = DP; T = TP; col = f; }
  else         { Dm = DQ; T = TQ; col = f - KK1; }
  float a = 0.f;
  for (int p = 0; p < SEGC; p++) a += Dm[(long)(s * SEGC + p) * KK1 + col];
  T[(long)s * KK1 + col] = a;
}

// ---------- scan: S[c] = S[0] + prefix(T) + in-segment prefix(D) ----------
__global__ __launch_bounds__(256) void k_scan(float* __restrict__ SP,
                                              float* __restrict__ SQ,
                                              const float* __restrict__ DP,
                                              const float* __restrict__ DQ,
                                              const float* __restrict__ TP,
                                              const float* __restrict__ TQ) {
  int f = blockIdx.x * 256 + threadIdx.x;   // < 16640
  int s = blockIdx.y;
  float* S; const float* Dm; const float* T; int col;
  if (f < KK1) { S = SP; Dm = DP; T = TP; col = f; }
  else         { S = SQ; Dm = DQ; T = TQ; col = f - KK1; }
  float acc = S[col];                       // row 0 (never rewritten)
  for (int sp = 0; sp < s; sp++) acc += T[(long)sp * KK1 + col];
  for (int p = 0; p < SEGC; p++) {
    int c = s * SEGC + p;
    if (c > 0) S[(long)c * KK1 + col] = acc;
    acc += Dm[(long)c * KK1 + col];
  }
}

// ---------- per-chunk sweep, i-split (contiguous halves); msg write, no atomics ----------
#define EC 192
#define KC 128
__global__ __launch_bounds__(256) void k_sweep(const float* __restrict__ SP,
                                               const float* __restrict__ SQ,
                                               const float* __restrict__ W1a,
                                               const float* __restrict__ b1a,
                                               const float* __restrict__ W1b,
                                               const float* __restrict__ x,
                                               const float* __restrict__ eattr,
                                               const int* __restrict__ ei,
                                               const int* __restrict__ e_off,
                                               const int* __restrict__ e_idx,
                                               const int* __restrict__ k_off,
                                               const int* __restrict__ k_idx,
                                               float* __restrict__ msg) {
  __shared__ float Pl[KHW], Ql[KHW];
  __shared__ float eas[EC], eas_r[EC];
  __shared__ int eix[EC], eix_r[EC];
  __shared__ float tks[KC], tks_r[KC];
  __shared__ int kix[KC], kix_r[KC];
  int c = blockIdx.x, ih = blockIdx.y, t = threadIdx.x;
  int jb = ih * KHW;                        // contiguous column base
  int eb = e_off[c], ne = e_off[c + 1] - eb; if (ne > EC) ne = EC;
  int kb = k_off[c], nk = k_off[c + 1] - kb; if (nk > KC) nk = KC;
  for (int j = t; j < KHW; j += 256) {
    Pl[j] = SP[(long)c * KK1 + jb + j];
    Ql[j] = SQ[(long)c * KK1 + jb + j];
  }
  if (t < ne) { int e = e_idx[eb + t]; eix_r[t] = e; eas_r[t] = eattr[e]; }
  if (t < nk) {
    int k = k_idx[kb + t];
    kix_r[t] = k;
    tks_r[t] = -b1a[k] / W1a[k];
  }
  __syncthreads();
  if (t < ne) {  // rank sort edges by ea
    float key = eas_r[t]; int rk = 0;
    for (int j = 0; j < ne; j++) { float kj = eas_r[j]; rk += (kj < key) || (kj == key && j < t); }
    eas[rk] = key; eix[rk] = eix_r[t];
  }
  if (t < nk) {  // rank sort events by threshold
    float key = tks_r[t]; int rk = 0;
    for (int j = 0; j < nk; j++) { float kj = tks_r[j]; rk += (kj < key) || (kj == key && j < t); }
    tks[rk] = key; kix[rk] = kix_r[t];
  }
  __syncthreads();
  if (ne == 0) return;
  int ie = 0, ik = 0;
  int q = t >> 6, o = t & 63;               // 4 edge slots x 64 outputs
  float* mbase = msg + (long)ih * (NE * 64);
  while (ie < ne) {
    int me = 0;
    while (ik + me < nk && tks[ik + me] < eas[ie]) me++;
    if (me > 0) {
      __syncthreads();                      // prior edge reads of Pl/Ql done
      for (int ev = 0; ev < me; ev++) {     // threads own disjoint j's: no inner barrier
        int k = kix[ik + ev];
        float a = W1a[k], c2 = b1a[k];
        float sa = (a > 0.f) ? a : -a;
        float sc = (a > 0.f) ? c2 : -c2;
        const float* row = &W1b[(long)k * KK1 + jb];
        for (int j = t; j < KHW; j += 256) {
          float w = row[j];
          Pl[j] = fmaf(sa, w, Pl[j]);
          Ql[j] = fmaf(sc, w, Ql[j]);
        }
      }
      __syncthreads();
      ik += me;
    }
    int m = 1;
    while (ie + m < ne && (ik >= nk || eas[ie + m] <= tks[ik])) m++;
    for (int g = 0; g < m; g += 4) {
      int sl = g + q;
      if (sl < m) {
        int e = eix[ie + sl];
        float eav = eas[ie + sl];
        int s = ei[e];
        const float* xp = &x[s * DD + ih * 65];
        float A = 0.f, B = 0.f;
#pragma unroll 5
        for (int i = 0; i < 65; i++) {
          float xv = xp[i];
          A = fmaf(xv, Pl[i * 64 + o], A);
          B = fmaf(xv, Ql[i * 64 + o], B);
        }
        mbase[e * 64 + o] = fmaf(eav, A, B);
      }
    }
    ie += m;
  }
}

// ---------- gather msg halves by dst-CSR + mean + root + bias + relu ----------
__global__ __launch_bounds__(256) void k_aggh(const float* __restrict__ msg,
                                              const int* __restrict__ d_off,
                                              const int* __restrict__ perm_dst,
                                              const float* __restrict__ xr1,
                                              const float* __restrict__ bc1,
                                              float* __restrict__ h1) {
  int f = blockIdx.x * 256 + threadIdx.x;   // < 8192
  int n = f >> 6, o = f & 63;
  int b0 = d_off[n], b1 = d_off[n + 1];
  float v = 0.f;
  for (int r = b0; r < b1; r++) {
    int e = perm_dst[r];
    v += msg[e * 64 + o] + msg[NE * 64 + e * 64 + o];
  }
  float cn = fmaxf((float)(b1 - b0), 1.f);
  h1[f] = fmaxf(0.f, v / cn + xr1[f] + bc1[o]);
}

// ---------- fused: G2 = h1-dependent per-src weights, hb2/hr2 small mats ----------
__global__ __launch_bounds__(256) void k_g2s(const float* __restrict__ h1,
                                             const float* __restrict__ W2b,
                                             const float* __restrict__ b2b,
                                             const float* __restrict__ Wr2,
                                             float* __restrict__ G2,
                                             float* __restrict__ hb2,
                                             float* __restrict__ hr2) {
  int bx = blockIdx.x, t = threadIdx.x;
  if (bx < 2048) {
    int f = bx * 256 + t;  // < 128*64*64
    int s = f >> 12, k = (f >> 6) & 63, o = f & 63;
    const float* hp = &h1[s * 64];
    const float* wp = &W2b[k * 4096 + o];
    float a = 0.f;
    for (int i = 0; i < 64; i++) a = fmaf(hp[i], wp[i * 64], a);
    G2[f] = a;
  } else {
    int f = (bx - 2048) * 256 + t;  // < 8192
    int n = f >> 6, o = f & 63;
    float a = 0.f, b = 0.f;
    for (int i = 0; i < 64; i++) {
      float hv = h1[n * 64 + i];
      a = fmaf(hv, b2b[i * 64 + o], a);
      b = fmaf(hv, Wr2[i * 64 + o], b);
    }
    hb2[f] = a; hr2[f] = b;
  }
}

// ---------- conv2: dst-gather (CSR), no atomics; agg2 fully written ----------
__global__ __launch_bounds__(256) void k_consume2(const float* __restrict__ G2,
                                                  const float* __restrict__ W2a,
                                                  const float* __restrict__ b2a,
                                                  const float* __restrict__ eattr,
                                                  const int* __restrict__ ei,
                                                  const int* __restrict__ d_off,
                                                  const int* __restrict__ perm_dst,
                                                  const float* __restrict__ hb2,
                                                  float* __restrict__ agg2) {
  __shared__ float wa[64], wb[64];
  __shared__ float red[8][32];
  int n = blockIdx.x, oh = blockIdx.y, t = threadIdx.x;
  int sl = t >> 5, ol = t & 31;
  if (t < 64) { wa[t] = W2a[t]; wb[t] = b2a[t]; }
  __syncthreads();
  int b0 = d_off[n], b1 = d_off[n + 1];
  float acc = 0.f;
  for (int r = b0 + sl; r < b1; r += 8) {
    int e = perm_dst[r];
    int s = ei[e];
    float ev = eattr[e];
    const float* gp = &G2[s * 4096 + oh * 32 + ol];
    float a = hb2[s * 64 + oh * 32 + ol];
    for (int k = 0; k < 64; k++) {
      float u = fmaxf(0.f, fmaf(ev, wa[k], wb[k]));
      a = fmaf(u, gp[k * 64], a);
    }
    acc += a;
  }
  red[sl][ol] = acc;
  __syncthreads();
  if (sl == 0) {
    float a = 0.f;
#pragma unroll
    for (int j = 0; j < 8; j++) a += red[j][ol];
    agg2[n * 64 + oh * 32 + ol] = a;
  }
}

// ---------- h2 = relu(agg2/cnt + hr2 + bc2), cnt from d_off ----------
__global__ __launch_bounds__(256) void k_h2d(const float* __restrict__ agg,
                                             const int* __restrict__ d_off,
                                             const float* __restrict__ xr,
                                             const float* __restrict__ bc,
                                             float* __restrict__ h) {
  int f = blockIdx.x * 256 + threadIdx.x;  // < 8192
  int n = f >> 6, o = f & 63;
  float c = fmaxf((float)(d_off[n + 1] - d_off[n]), 1.f);
  h[f] = fmaxf(0.f, agg[f] / c + xr[f] + bc[o]);
}

// ---------- logits -> masked softmax -> packet-mask rows ----------
__global__ __launch_bounds__(128) void k_out(const float* __restrict__ h2,
                                             const float* __restrict__ Wout,
                                             const float* __restrict__ bout,
                                             const int* __restrict__ adj,
                                             const float* __restrict__ npk,
                                             float* __restrict__ out) {
  __shared__ float hs[64];
  __shared__ float redm[2], reds[2];
  int n = blockIdx.x, j = threadIdx.x;
  if (j < 64) hs[j] = h2[n * 64 + j];
  __syncthreads();
  float l = bout[j];
  for (int k = 0; k < 64; k++) l = fmaf(hs[k], Wout[k * 128 + j], l);
  bool am = adj[n * 128 + j] != 0;
  float lm = am ? l : -3.0e38f;
  float m = lm;
  for (int off = 32; off >= 1; off >>= 1) m = fmaxf(m, __shfl_xor(m, off, 64));
  int wid = j >> 6;
  if ((j & 63) == 0) redm[wid] = m;
  __syncthreads();
  m = fmaxf(redm[0], redm[1]);
  float p = am ? expf(lm - m) : 0.f;
  float sv = p;
  for (int off = 32; off >= 1; off >>= 1) sv += __shfl_xor(sv, off, 64);
  if ((j & 63) == 0) reds[wid] = sv;
  __syncthreads();
  sv = reds[0] + reds[1];
  float prob = p / sv;
  bool haspkt = (npk[n] != -1.0f);
  out[n * 128 + j] = haspkt ? prob : ((j == n) ? 1.f : 0.f);
}

extern "C" void kernel_launch(void* const* d_in, const int* in_sizes, int n_in,
                              void* d_out, int out_size, void* d_ws, size_t ws_size,
                              hipStream_t stream) {
  const float* x    = (const float*)d_in[0];
  const int*   ei   = (const int*)  d_in[1];
  const float* ea   = (const float*)d_in[2];
  const int*   adj  = (const int*)  d_in[3];
  const float* npk  = (const float*)d_in[4];
  const float* W1a  = (const float*)d_in[5];
  const float* b1a  = (const float*)d_in[6];
  const float* W1b  = (const float*)d_in[7];
  const float* b1b  = (const float*)d_in[8];
  const float* Wr1  = (const float*)d_in[9];
  const float* bc1  = (const float*)d_in[10];
  const float* W2a  = (const float*)d_in[11];
  const float* b2a  = (const float*)d_in[12];
  const float* W2b  = (const float*)d_in[13];
  const float* b2b  = (const float*)d_in[14];
  const float* Wr2  = (const float*)d_in[15];
  const float* bc2  = (const float*)d_in[16];
  const float* Wout = (const float*)d_in[17];
  const float* bout = (const float*)d_in[18];

  float* ws = (float*)d_ws;
  int*   ip = (int*)(ws + OFF_INT);
  int* e_off    = ip;
  int* k_off    = ip + 257;
  int* e_idx    = ip + 514;
  int* k_idx    = ip + 4610;
  int* base_idx = ip + 12930;
  int* nbase    = ip + 21250;
  int* d_off    = ip + 21251;
  int* perm_dst = ip + 21380;

  k_count<<<1, 256, 0, stream>>>(ei, ea, W1a, b1a, e_off, k_off, e_idx, k_idx,
                                 base_idx, nbase, d_off, perm_dst);
  k_pre<<<33, 256, 0, stream>>>(b1b, x, Wr1, ws + OFF_SP, ws + OFF_SQ, ws + OFF_XR1);
  k_base<<<128, 256, 0, stream>>>(W1a, b1a, W1b, base_idx, nbase,
                                  ws + OFF_SP, ws + OFF_SQ);
  k_diff<<<CC, 256, 0, stream>>>(W1a, b1a, W1b, k_off, k_idx, ws + OFF_DP, ws + OFF_DQ);
  k_seg<<<dim3(65, NSEG), 256, 0, stream>>>(ws + OFF_DP, ws + OFF_DQ,
                                            ws + OFF_TP, ws + OFF_TQ);
  k_scan<<<dim3(65, NSEG), 256, 0, stream>>>(ws + OFF_SP, ws + OFF_SQ,
                                             ws + OFF_DP, ws + OFF_DQ,
                                             ws + OFF_TP, ws + OFF_TQ);
  k_sweep<<<dim3(CC, 2), 256, 0, stream>>>(ws + OFF_SP, ws + OFF_SQ, W1a, b1a, W1b,
                                           x, ea, ei, e_off, e_idx, k_off, k_idx,
                                           ws + OFF_MSG);
  k_aggh<<<32, 256, 0, stream>>>(ws + OFF_MSG, d_off, perm_dst, ws + OFF_XR1, bc1,
                                 ws + OFF_H1);
  k_g2s<<<2080, 256, 0, stream>>>(ws + OFF_H1, W2b, b2b, Wr2,
                                  ws + OFF_G2, ws + OFF_HB2, ws + OFF_HR2);
  k_consume2<<<dim3(NN, 2), 256, 0, stream>>>(ws + OFF_G2, W2a, b2a, ea, ei,
                                              d_off, perm_dst, ws + OFF_HB2,
                                              ws + OFF_AGG2);
  k_h2d<<<32, 256, 0, stream>>>(ws + OFF_AGG2, d_off, ws + OFF_HR2, bc2, ws + OFF_H2);
  k_out<<<128, 128, 0, stream>>>(ws + OFF_H2, Wout, bout, adj, npk, (float*)d_out);
}